// Round 1
// baseline (83.645 us; speedup 1.0000x reference)
//
#include <hip/hip_runtime.h>

#define SEQ_LEN 512
#define EMBED_DIM 768
#define WIDTH_EMB 50
#define NUM_LABELS 9
#define N_SPANS 32768
#define WROW (3 * EMBED_DIM + WIDTH_EMB)   // 2354

// ws layout (floats): P1[512*9] | P2[512*9] | P3[512*9] | WP[17*9]
#define P1_OFF 0
#define P2_OFF (SEQ_LEN * NUM_LABELS)
#define P3_OFF (2 * SEQ_LEN * NUM_LABELS)
#define WP_OFF (3 * SEQ_LEN * NUM_LABELS)

// One wave per token: computes the 27 projections (3 segments x 9 labels)
// via per-lane partial dots + butterfly reduce. Block 512 handles the
// width-table projection (+bias).
__global__ __launch_bounds__(64) void proj_kernel(
    const float* __restrict__ seq,    // [512*768]
    const float* __restrict__ wtab,   // [17*50]
    const float* __restrict__ W,      // [9*2354]
    const float* __restrict__ b,      // [9]
    float* __restrict__ ws)
{
    const int blk  = blockIdx.x;
    const int lane = threadIdx.x;

    if (blk < SEQ_LEN) {
        const float* srow = seq + blk * EMBED_DIM;
        float s[12];
#pragma unroll
        for (int k = 0; k < 12; ++k) s[k] = srow[lane + 64 * k];

#pragma unroll
        for (int seg = 0; seg < 3; ++seg) {
#pragma unroll
            for (int l = 0; l < NUM_LABELS; ++l) {
                const float* wrow = W + l * WROW + seg * EMBED_DIM;
                float p = 0.f;
#pragma unroll
                for (int k = 0; k < 12; ++k) p += s[k] * wrow[lane + 64 * k];
                // wave-64 butterfly reduction
#pragma unroll
                for (int off = 32; off > 0; off >>= 1)
                    p += __shfl_xor(p, off, 64);
                if (lane == 0)
                    ws[seg * (SEQ_LEN * NUM_LABELS) + blk * NUM_LABELS + l] = p;
            }
        }
    } else {
        // WP[w][l] = b[l] + width_table[w] . W[l, 2304:2354]
        for (int idx = lane; idx < 17 * NUM_LABELS; idx += 64) {
            int w = idx / NUM_LABELS;
            int l = idx - w * NUM_LABELS;
            const float* wrow = W + l * WROW + 3 * EMBED_DIM;
            const float* trow = wtab + w * WIDTH_EMB;
            float p = b[l];
            for (int j = 0; j < WIDTH_EMB; ++j) p += trow[j] * wrow[j];
            ws[WP_OFF + idx] = p;
        }
    }
}

// One thread per (span, label) output.
__global__ __launch_bounds__(256) void span_kernel(
    const int* __restrict__ start_idx,
    const int* __restrict__ end_idx,
    const int* __restrict__ widths,
    const float* __restrict__ ws,
    float* __restrict__ out)
{
    const int i = blockIdx.x * blockDim.x + threadIdx.x;
    if (i >= N_SPANS * NUM_LABELS) return;
    const int n = i / NUM_LABELS;
    const int l = i - n * NUM_LABELS;

    const int s = start_idx[n];
    const int e = end_idx[n];
    const int w = widths[n];

    const float* P1 = ws + P1_OFF;
    const float* P2 = ws + P2_OFF;
    const float* P3 = ws + P3_OFF;
    const float* WP = ws + WP_OFF;

    float acc = P1[s * NUM_LABELS + l] + P2[e * NUM_LABELS + l]
              + WP[w * NUM_LABELS + l];
    float sum = 0.f;
    for (int t = s; t < e; ++t) sum += P3[t * NUM_LABELS + l];
    out[i] = acc + sum / (float)w;
}

extern "C" void kernel_launch(void* const* d_in, const int* in_sizes, int n_in,
                              void* d_out, int out_size, void* d_ws, size_t ws_size,
                              hipStream_t stream) {
    const float* seq  = (const float*)d_in[0];
    const int*   s    = (const int*)d_in[1];
    const int*   e    = (const int*)d_in[2];
    const int*   w    = (const int*)d_in[3];
    const float* wtab = (const float*)d_in[4];
    const float* W    = (const float*)d_in[5];
    const float* b    = (const float*)d_in[6];
    float* out = (float*)d_out;
    float* ws  = (float*)d_ws;

    proj_kernel<<<SEQ_LEN + 1, 64, 0, stream>>>(seq, wtab, W, b, ws);

    const int total = N_SPANS * NUM_LABELS;
    span_kernel<<<(total + 255) / 256, 256, 0, stream>>>(s, e, w, ws, out);
}

// Round 2
// 83.082 us; speedup vs baseline: 1.0068x; 1.0068x over previous
//
#include <hip/hip_runtime.h>

#define SEQ_LEN 512
#define EMBED_DIM 768
#define WIDTH_EMB 50
#define NUM_LABELS 9
#define N_SPANS 32768
#define WROW (3 * EMBED_DIM + WIDTH_EMB)   // 2354

// ws layout (floats): P1[512*9] | P2[512*9] | P3[512*9] | WP[17*9]
#define P1_OFF 0
#define P2_OFF (SEQ_LEN * NUM_LABELS)
#define P3_OFF (2 * SEQ_LEN * NUM_LABELS)
#define WP_OFF (3 * SEQ_LEN * NUM_LABELS)

// One wave per token: computes the 27 projections (3 segments x 9 labels)
// via per-lane partial dots (float2 vector loads; W rows are 8B-aligned,
// 2354*4 stride, so float4 would misalign) + wave-64 butterfly reduce.
// Block SEQ_LEN handles the width-table projection (+bias).
__global__ __launch_bounds__(64) void proj_kernel(
    const float* __restrict__ seq,    // [512*768]
    const float* __restrict__ wtab,   // [17*50]
    const float* __restrict__ W,      // [9*2354]
    const float* __restrict__ b,      // [9]
    float* __restrict__ ws)
{
    const int blk  = blockIdx.x;
    const int lane = threadIdx.x;

    if (blk < SEQ_LEN) {
        const float2* srow = (const float2*)(seq + blk * EMBED_DIM); // 384 f2
        float2 s2[6];
#pragma unroll
        for (int k = 0; k < 6; ++k) s2[k] = srow[lane + 64 * k];

#pragma unroll
        for (int seg = 0; seg < 3; ++seg) {
#pragma unroll
            for (int l = 0; l < NUM_LABELS; ++l) {
                const float2* wrow =
                    (const float2*)(W + l * WROW + seg * EMBED_DIM);
                float p = 0.f;
#pragma unroll
                for (int k = 0; k < 6; ++k) {
                    float2 wv = wrow[lane + 64 * k];
                    p += s2[k].x * wv.x + s2[k].y * wv.y;
                }
#pragma unroll
                for (int off = 32; off > 0; off >>= 1)
                    p += __shfl_xor(p, off, 64);
                if (lane == 0)
                    ws[seg * (SEQ_LEN * NUM_LABELS) + blk * NUM_LABELS + l] = p;
            }
        }
    } else {
        // WP[w][l] = b[l] + width_table[w] . W[l, 2304:2354]
        for (int idx = lane; idx < 17 * NUM_LABELS; idx += 64) {
            int w = idx / NUM_LABELS;
            int l = idx - w * NUM_LABELS;
            const float* wrow = W + l * WROW + 3 * EMBED_DIM;
            const float* trow = wtab + w * WIDTH_EMB;
            float p = b[l];
            for (int j = 0; j < WIDTH_EMB; ++j) p += trow[j] * wrow[j];
            ws[WP_OFF + idx] = p;
        }
    }
}

// 576 threads = 9 waves = 64 spans/block, one thread per (span,label).
// P3 + WP staged in LDS; ragged-mean loop reads LDS, not L1.
#define SPB 64
__global__ __launch_bounds__(576) void span_kernel(
    const int* __restrict__ start_idx,
    const int* __restrict__ end_idx,
    const int* __restrict__ widths,
    const float* __restrict__ ws,
    float* __restrict__ out)
{
    __shared__ float sP3[SEQ_LEN * NUM_LABELS];   // 18432 B
    __shared__ float sWP[17 * NUM_LABELS];

    const int t = threadIdx.x;
    for (int i = t; i < SEQ_LEN * NUM_LABELS; i += 576)
        sP3[i] = ws[P3_OFF + i];
    if (t < 17 * NUM_LABELS)
        sWP[t] = ws[WP_OFF + t];
    __syncthreads();

    const int n = blockIdx.x * SPB + t / NUM_LABELS;
    const int l = t - (t / NUM_LABELS) * NUM_LABELS;

    const int s = start_idx[n];
    const int e = end_idx[n];
    const int w = widths[n];

    float acc = ws[P1_OFF + s * NUM_LABELS + l]
              + ws[P2_OFF + e * NUM_LABELS + l]
              + sWP[w * NUM_LABELS + l];
    float sum = 0.f;
    for (int k = s; k < e; ++k) sum += sP3[k * NUM_LABELS + l];
    out[blockIdx.x * (SPB * NUM_LABELS) + t] = acc + sum / (float)w;
}

extern "C" void kernel_launch(void* const* d_in, const int* in_sizes, int n_in,
                              void* d_out, int out_size, void* d_ws, size_t ws_size,
                              hipStream_t stream) {
    const float* seq  = (const float*)d_in[0];
    const int*   s    = (const int*)d_in[1];
    const int*   e    = (const int*)d_in[2];
    const int*   w    = (const int*)d_in[3];
    const float* wtab = (const float*)d_in[4];
    const float* W    = (const float*)d_in[5];
    const float* b    = (const float*)d_in[6];
    float* out = (float*)d_out;
    float* ws  = (float*)d_ws;

    proj_kernel<<<SEQ_LEN + 1, 64, 0, stream>>>(seq, wtab, W, b, ws);

    span_kernel<<<N_SPANS / SPB, 576, 0, stream>>>(s, e, w, ws, out);
}